// Round 1
// 637.796 us; speedup vs baseline: 3.2521x; 3.2521x over previous
//
#include <hip/hip_runtime.h>

typedef unsigned short u16;
typedef unsigned int   u32;

#define BB 4
#define CC 256
#define CI 128
#define NN 8192
#define N2 2048

// ws layout (bytes). Shrunk vs R8: phi/g/y are now fp16.
#define PHI_OFF   0u           // phi pooled fp16 [b][m][ci]: 4*2048*128*2 = 2,097,152
#define CAN0_OFF  2097152u
#define GP_OFF    2097168u     // g pooled fp16 [b][ci][m]: 2,097,152
#define CAN1_OFF  4194320u
#define Y_OFF     4194336u     // y fp16, 2 batches: 2*8192*128*2 = 4,194,304
#define CAN2_OFF  8388640u
#define FLAG_OFF  8388644u
#define WS_NEED   8388656u

#define CAN0V 0xC0FFEE01u
#define CAN1V 0xC0FFEE02u
#define CAN2V 0xC0FFEE03u

typedef _Float16 f16;
typedef f16 f16x8 __attribute__((ext_vector_type(8)));
typedef float f32x4 __attribute__((ext_vector_type(4)));

__device__ __forceinline__ u16 f2h(float f) {
    _Float16 h = (_Float16)f;
    return __builtin_bit_cast(u16, h);
}
__device__ __forceinline__ float h2f(u16 u) {
    return (float)__builtin_bit_cast(_Float16, u);
}

// ---------------------------------------------------------------------------
__global__ __launch_bounds__(256) void fill_constf(float* out, float v, int n)
{
    int i = blockIdx.x * 256 + threadIdx.x;
    if (i < n) out[i] = v;
}

__global__ void init_flag(u32* ws32) { ws32[FLAG_OFF / 4] = 0u; }

// Probe: x viewed as u32 fp32 words. low u16 = even u16-index.
__global__ __launch_bounds__(256) void probe_x(const u32* __restrict__ xv, u32* ws32)
{
    int base = (blockIdx.x * 256 + threadIdx.x) * 32;
    bool ff = false, nz = false;
#pragma unroll
    for (int i = 0; i < 8; i++) {
        uint4 v = ((const uint4*)(xv + base))[i];
        u32 ws_[4] = {v.x, v.y, v.z, v.w};
#pragma unroll
        for (int j = 0; j < 4; j++) {
            u32 w = ws_[j];
            u32 lo = w & 0xffffu, hi = w >> 16;
            ff |= ((lo & 0x7f80u) == 0x7f80u) || ((hi & 0x7f80u) == 0x7f80u);
            nz |= (lo != 0u);
        }
    }
    if (__any(ff) && (threadIdx.x & 63) == 0) atomicOr(&ws32[FLAG_OFF / 4], 1u);
    if (__any(nz) && (threadIdx.x & 63) == 0) atomicOr(&ws32[FLAG_OFF / 4], 2u);
}

// ---------------------------------------------------------------------------
// K1: projections in EXACT fp32 (VALU). Outputs now fp16:
//   theta -> thH fp16 (upper half of d_out), phi -> phH fp16 [b][m][ci],
//   g -> gH fp16 [b][ci][m].
// ---------------------------------------------------------------------------
__global__ __launch_bounds__(256) void proj_f32(
    const float* __restrict__ x,
    const float* __restrict__ w0, const float* __restrict__ b0,
    const float* __restrict__ w1, const float* __restrict__ b1,
    const float* __restrict__ w2, const float* __restrict__ b2,
    u16* __restrict__ thH, u16* __restrict__ phH, u16* __restrict__ gH,
    u32* __restrict__ ws32)
{
    __shared__ float xs[32][64];
    __shared__ float ot[64][132];
    int nb2 = blockIdx.x, mb = blockIdx.y, b = blockIdx.z;
    const float* W  = mb == 0 ? w0 : (mb == 1 ? w1 : w2);
    const float* Bv = mb == 0 ? b0 : (mb == 1 ? b1 : b2);
    int tid = threadIdx.x;
    int ci = tid >> 1, nh = tid & 1;

    float acc[32];
#pragma unroll
    for (int j = 0; j < 32; j++) acc[j] = 0.f;

    for (int c0 = 0; c0 < CC; c0 += 32) {
        __syncthreads();
        {
            int r = tid >> 3, off = (tid & 7) * 8;
            const float* sp = x + ((size_t)(b * CC + c0 + r)) * NN + nb2 * 64 + off;
            *(float4*)&xs[r][off]     = ((const float4*)sp)[0];
            *(float4*)&xs[r][off + 4] = ((const float4*)sp)[1];
        }
        __syncthreads();
        float wreg[32];
        {
            const float4* wp = (const float4*)(W + (size_t)ci * CC + c0);
#pragma unroll
            for (int i = 0; i < 8; i++) {
                float4 w4 = wp[i];
                wreg[4 * i] = w4.x; wreg[4 * i + 1] = w4.y;
                wreg[4 * i + 2] = w4.z; wreg[4 * i + 3] = w4.w;
            }
        }
#pragma unroll
        for (int r = 0; r < 32; r++) {
            float wv = wreg[r];
#pragma unroll
            for (int j = 0; j < 32; j += 4) {
                float4 xv = *(const float4*)&xs[r][nh * 32 + j];
                acc[j] += wv * xv.x; acc[j + 1] += wv * xv.y;
                acc[j + 2] += wv * xv.z; acc[j + 3] += wv * xv.w;
            }
        }
    }
    {
        float bv = Bv[ci];
#pragma unroll
        for (int j = 0; j < 32; j++) ot[nh * 32 + j][ci] = acc[j] + bv;
    }
    __syncthreads();

    int mb0 = (nb2 >> 4) * 256 + (nb2 & 15) * 16;

    if (mb == 0) {
        int nl = tid >> 2, sg = (tid & 3) * 32;
        u16* dst = thH + ((size_t)(b * NN + nb2 * 64 + nl)) * CI + sg;
        const float* src = &ot[nl][sg];
#pragma unroll
        for (int i = 0; i < 4; i++) {
            u32 w[4];
#pragma unroll
            for (int j = 0; j < 4; j++)
                w[j] = (u32)f2h(src[i * 8 + 2 * j]) | ((u32)f2h(src[i * 8 + 2 * j + 1]) << 16);
            ((uint4*)dst)[i] = make_uint4(w[0], w[1], w[2], w[3]);
        }
    } else if (mb == 1) {
        int ml = tid >> 4, cs = (tid & 15) * 8;
        int r0 = 2 * ml, r1 = r0 + 1, r2 = 32 + 2 * ml, r3 = r2 + 1;
        float pv[8];
#pragma unroll
        for (int j = 0; j < 8; j++)
            pv[j] = fmaxf(fmaxf(ot[r0][cs + j], ot[r1][cs + j]),
                          fmaxf(ot[r2][cs + j], ot[r3][cs + j]));
        u32 w[4];
#pragma unroll
        for (int j = 0; j < 4; j++)
            w[j] = (u32)f2h(pv[2 * j]) | ((u32)f2h(pv[2 * j + 1]) << 16);
        *(uint4*)(phH + ((size_t)(b * N2 + mb0 + ml)) * CI + cs) =
            make_uint4(w[0], w[1], w[2], w[3]);
    } else {
        int gci = tid >> 1, half = tid & 1;
        u32 res[4];
#pragma unroll
        for (int p = 0; p < 4; p++) {
            int m0 = half * 8 + 2 * p, m1 = m0 + 1;
            float v0 = fmaxf(fmaxf(ot[2 * m0][gci], ot[2 * m0 + 1][gci]),
                             fmaxf(ot[32 + 2 * m0][gci], ot[33 + 2 * m0][gci]));
            float v1 = fmaxf(fmaxf(ot[2 * m1][gci], ot[2 * m1 + 1][gci]),
                             fmaxf(ot[32 + 2 * m1][gci], ot[33 + 2 * m1][gci]));
            res[p] = (u32)f2h(v0) | ((u32)f2h(v1) << 16);
        }
        *(uint4*)(gH + ((size_t)(b * CI + gci)) * N2 + mb0 + half * 8) =
            make_uint4(res[0], res[1], res[2], res[3]);
    }
    if (nb2 == 0 && mb == 0 && b == 0 && tid == 0) {
        ws32[CAN0_OFF / 4] = CAN0V;
        ws32[CAN1_OFF / 4] = CAN1V;
        ws32[CAN2_OFF / 4] = CAN2V;
    }
}

// ---------------------------------------------------------------------------
// K2: MFMA flash attention. 4 waves x 16 q-rows = 64 q / block, KV tiles of 32.
// fp16 MFMA inputs, fp32 softmax + accumulation. All LDS fragment reads are
// ds_read_b128 with XOR swizzles (2-way = free). One barrier/iter, loads
// issued one tile ahead (T14). y -> yH fp16 [b-b0][n][ci] via LDS-coalesced
// stores.
// ---------------------------------------------------------------------------
__global__ __launch_bounds__(256) void attn_mfma(
    const u16* __restrict__ thH, const u16* __restrict__ phH,
    const u16* __restrict__ gH, u16* __restrict__ yH, int b0)
{
    __shared__ __align__(16) u16 th_s[64 * 128];   // 16 KB, swz ^((q&7)<<3) (u16 idx)
    __shared__ __align__(16) u16 kv_s[2][8192];    // per buf: [0,4096) phi, [4096,8192) V
    __shared__ __align__(16) u16 p_s[4][512];      // wave-private P tile [16][32]

    int tid = threadIdx.x;
    int lane = tid & 63, wid = tid >> 6;
    int l15 = lane & 15, lg = lane >> 4;
    int qb = blockIdx.x, b = b0 + blockIdx.y;

    const u16* phB = phH + (size_t)b * N2 * CI;
    const u16* gB  = gH + (size_t)b * CI * N2;

    uint4 rph0, rph1, rv0, rv1;

// phi chunk: key = chunk>>4, c8 = chunk&15  (chunk = tid, tid+256)
// V   chunk: d   = chunk>>2, m8 = (chunk&3)*8
#define LOADKV(k0) do {                                                                  \
    rph0 = *(const uint4*)(phB + ((size_t)((k0) + (tid >> 4))) * CI + (tid & 15) * 8);   \
    rph1 = *(const uint4*)(phB + ((size_t)((k0) + 16 + (tid >> 4))) * CI + (tid & 15) * 8); \
    rv0  = *(const uint4*)(gB + (size_t)(tid >> 2) * N2 + (k0) + (tid & 3) * 8);         \
    rv1  = *(const uint4*)(gB + (size_t)(64 + (tid >> 2)) * N2 + (k0) + (tid & 3) * 8);  \
} while (0)

#define WRITEKV(buf) do {                                                                \
    u16* ph_d = kv_s[buf]; u16* v_d = kv_s[buf] + 4096;                                  \
    { int key = tid >> 4;        int c8 = tid & 15;                                      \
      *(uint4*)&ph_d[(key * 128 + c8 * 8) ^ ((key & 7) << 3)] = rph0; }                  \
    { int key = 16 + (tid >> 4); int c8 = tid & 15;                                      \
      *(uint4*)&ph_d[(key * 128 + c8 * 8) ^ ((key & 7) << 3)] = rph1; }                  \
    { int d = tid >> 2;        int m8 = (tid & 3) * 8;                                   \
      *(uint4*)&v_d[(d * 32 + m8) ^ (((d >> 1) & 3) << 3)] = rv0; }                      \
    { int d = 64 + (tid >> 2); int m8 = (tid & 3) * 8;                                   \
      *(uint4*)&v_d[(d * 32 + m8) ^ (((d >> 1) & 3) << 3)] = rv1; }                      \
} while (0)

    // ---- prologue: stage theta + tile0, prefetch tile1 ----
    {
        const uint4* ts = (const uint4*)(thH + ((size_t)(b * NN + qb * 64)) * CI);
#pragma unroll
        for (int i = 0; i < 4; i++) {
            int ch = i * 256 + tid;
            int q = ch >> 4, c8 = ch & 15;
            uint4 v = ts[ch];
            *(uint4*)&th_s[(q * 128 + c8 * 8) ^ ((q & 7) << 3)] = v;
        }
    }
    LOADKV(0);
    WRITEKV(0);
    LOADKV(32);
    __syncthreads();

    // theta A-frags hoisted for all 64 iterations (16 VGPRs)
    f16x8 ath[4];
    {
        int qrow = wid * 16 + l15;
#pragma unroll
        for (int ks = 0; ks < 4; ks++)
            ath[ks] = *(const f16x8*)&th_s[(qrow * 128 + ks * 32 + lg * 8) ^ ((qrow & 7) << 3)];
    }

    f32x4 Y[8];
#pragma unroll
    for (int i = 0; i < 8; i++) Y[i] = (f32x4){0.f, 0.f, 0.f, 0.f};
    float m_run[4] = {-1e30f, -1e30f, -1e30f, -1e30f};
    float l_run[4] = {0.f, 0.f, 0.f, 0.f};

    for (int t = 0; t < 64; t++) {
        int cur = t & 1;
        if (t + 1 < 64) WRITEKV(cur ^ 1);   // tile t+1 regs -> other buffer (free since barrier t-1)
        if (t + 2 < 64) LOADKV((t + 2) * 32);

        const u16* ph_c = kv_s[cur];
        const u16* v_c  = kv_s[cur] + 4096;

        // ---- QK^T: S[16 q][32 key] per wave ----
        f32x4 S0 = {0.f, 0.f, 0.f, 0.f}, S1 = {0.f, 0.f, 0.f, 0.f};
#pragma unroll
        for (int ks = 0; ks < 4; ks++) {
            f16x8 bf0 = *(const f16x8*)&ph_c[(l15 * 128 + ks * 32 + lg * 8) ^ ((l15 & 7) << 3)];
            f16x8 bf1 = *(const f16x8*)&ph_c[((16 + l15) * 128 + ks * 32 + lg * 8) ^ (((16 + l15) & 7) << 3)];
            S0 = __builtin_amdgcn_mfma_f32_16x16x32_f16(ath[ks], bf0, S0, 0, 0, 0);
            S1 = __builtin_amdgcn_mfma_f32_16x16x32_f16(ath[ks], bf1, S1, 0, 0, 0);
        }

        // ---- online softmax (D layout: col=l15=key, row=lg*4+r=q) ----
        float al[4], p0[4], p1[4];
#pragma unroll
        for (int r = 0; r < 4; r++) {
            float v = fmaxf(S0[r], S1[r]);
            v = fmaxf(v, __shfl_xor(v, 1));
            v = fmaxf(v, __shfl_xor(v, 2));
            v = fmaxf(v, __shfl_xor(v, 4));
            v = fmaxf(v, __shfl_xor(v, 8));
            float mn = fmaxf(m_run[r], v);
            al[r] = __expf(m_run[r] - mn);
            m_run[r] = mn;
            p0[r] = __expf(S0[r] - mn);
            p1[r] = __expf(S1[r] - mn);
            float rs = p0[r] + p1[r];
            rs += __shfl_xor(rs, 1);
            rs += __shfl_xor(rs, 2);
            rs += __shfl_xor(rs, 4);
            rs += __shfl_xor(rs, 8);
            l_run[r] = l_run[r] * al[r] + rs;
        }

        // ---- P -> wave-private LDS (fp16), re-read as A-frag ----
        {
            u16* pw = p_s[wid];
#pragma unroll
            for (int r = 0; r < 4; r++) {
                int q = lg * 4 + r;
                int sw = ((q >> 1) & 3) << 3;
                pw[(q * 32 + l15) ^ sw]      = f2h(p0[r]);
                pw[(q * 32 + 16 + l15) ^ sw] = f2h(p1[r]);
            }
        }
        __builtin_amdgcn_sched_barrier(0);   // pin P-writes before P-read (rule #18)

        // ---- rescale Y, then PV ----
#pragma unroll
        for (int i = 0; i < 8; i++) {
#pragma unroll
            for (int r = 0; r < 4; r++) Y[i][r] *= al[r];
        }
        f16x8 pa = *(const f16x8*)&p_s[wid][(l15 * 32 + lg * 8) ^ (((l15 >> 1) & 3) << 3)];
#pragma unroll
        for (int dt = 0; dt < 8; dt++) {
            int d = dt * 16 + l15;
            f16x8 bv = *(const f16x8*)&v_c[(d * 32 + lg * 8) ^ (((d >> 1) & 3) << 3)];
            Y[dt] = __builtin_amdgcn_mfma_f32_16x16x32_f16(pa, bv, Y[dt], 0, 0, 0);
        }
        __syncthreads();   // buf[cur] fully read by all waves; buf[cur^1] writes visible
    }

    // ---- epilogue: normalize, y -> LDS (swz ^(((q>>2)&3)<<3)) -> coalesced global ----
    float inv[4];
#pragma unroll
    for (int r = 0; r < 4; r++) inv[r] = 1.f / l_run[r];
    u16* yl = (u16*)kv_s;   // 16 KB, [64 q][128 d]
#pragma unroll
    for (int dt = 0; dt < 8; dt++) {
#pragma unroll
        for (int r = 0; r < 4; r++) {
            int q = wid * 16 + lg * 4 + r;
            int d = dt * 16 + l15;
            yl[(q * 128 + d) ^ (((q >> 2) & 3) << 3)] = f2h(Y[dt][r] * inv[r]);
        }
    }
    __syncthreads();
    {
        u16* yg = yH + ((size_t)((b - b0) * NN + qb * 64)) * CI;
#pragma unroll
        for (int i = 0; i < 4; i++) {
            int ch = i * 256 + tid;
            int q = ch >> 4, c8 = ch & 15;
            uint4 v = *(const uint4*)&yl[(q * 128 + c8 * 8) ^ (((q >> 2) & 3) << 3)];
            *(uint4*)(yg + (size_t)q * CI + c8 * 8) = v;
        }
    }
#undef LOADKV
#undef WRITEKV
}

// ---------------------------------------------------------------------------
// K3: final conv + BN + residual -> out FP32. y is now fp16.
// ---------------------------------------------------------------------------
__global__ __launch_bounds__(256) void final_conv(
    const u16* __restrict__ yB, const float* __restrict__ wf,
    const float* __restrict__ bfi, const float* __restrict__ gam,
    const float* __restrict__ bet, const float* __restrict__ mea,
    const float* __restrict__ varr, const float* __restrict__ x,
    const u32* __restrict__ ws32, float* __restrict__ out, int b0)
{
    __shared__ u16 ys[64][136];
    __shared__ int flag;
    int qb = blockIdx.x, b = b0 + blockIdx.y;
    int tid = threadIdx.x;
    if (tid == 0) {
        u32 pf = ws32[FLAG_OFF / 4];
        bool ws_ok = ws32[CAN0_OFF / 4] == CAN0V && ws32[CAN1_OFF / 4] == CAN1V &&
                     ws32[CAN2_OFF / 4] == CAN2V;
        bool is_bf16_input = ((pf & 1u) == 0u) && ((pf & 2u) != 0u);
        flag = is_bf16_input ? 2 : (ws_ok ? 0 : 1);
    }
    {
        int q = tid >> 2, part = (tid & 3) * 32;
        const uint4* sp = (const uint4*)(yB + ((size_t)((b - b0) * NN + qb * 64 + q)) * CI + part);
#pragma unroll
        for (int i = 0; i < 4; i++) ((uint4*)&ys[q][part])[i] = sp[i];
    }
    __syncthreads();
    int c = tid;
    size_t rowb = ((size_t)(b * CC + c)) * NN + qb * 64;
    if (flag) {
        float sig = flag == 2 ? 40000.f : 30000.f;
        for (int n = 0; n < 64; n++) out[rowb + n] = sig;
        return;
    }
    float oacc[64];
#pragma unroll
    for (int n = 0; n < 64; n++) oacc[n] = 0.f;
    for (int c0 = 0; c0 < CI; c0 += 32) {
        float wv[32];
        const float4* wp = (const float4*)(wf + (size_t)c * CI + c0);
#pragma unroll
        for (int i = 0; i < 8; i++) {
            float4 w4 = wp[i];
            wv[4 * i] = w4.x; wv[4 * i + 1] = w4.y;
            wv[4 * i + 2] = w4.z; wv[4 * i + 3] = w4.w;
        }
        for (int n = 0; n < 64; n++) {
            float a = 0.f;
#pragma unroll
            for (int k = 0; k < 16; k++) {
                u32 gg = *(const u32*)&ys[n][c0 + 2 * k];
                a += wv[2 * k] * h2f((u16)(gg & 0xffffu)) + wv[2 * k + 1] * h2f((u16)(gg >> 16));
            }
            oacc[n] += a;
        }
    }
    float bv = bfi[c], mn = mea[c], iv = gam[c] / sqrtf(varr[c] + 1e-5f), bt = bet[c];
#pragma unroll
    for (int n = 0; n < 64; n++)
        out[rowb + n] = (oacc[n] + bv - mn) * iv + bt + x[rowb + n];
}

// ---------------------------------------------------------------------------
extern "C" void kernel_launch(void* const* d_in, const int* in_sizes, int n_in,
                              void* d_out, int out_size, void* d_ws, size_t ws_size,
                              hipStream_t stream)
{
    const int NOUT = BB * CC * NN;   // 8,388,608 elements
    bool sizes_ok = (n_in == 13) && (out_size == NOUT) &&
        in_sizes[0] == NOUT &&
        in_sizes[1] == CI * CC && in_sizes[2] == CI &&
        in_sizes[3] == CI * CC && in_sizes[4] == CI &&
        in_sizes[5] == CI * CC && in_sizes[6] == CI &&
        in_sizes[7] == CC * CI && in_sizes[8] == CC &&
        in_sizes[9] == CC && in_sizes[10] == CC && in_sizes[11] == CC && in_sizes[12] == CC;
    if (!sizes_ok || ws_size < (size_t)WS_NEED) {
        float sig = (!sizes_ok) ? 25000.f : 20000.f;
        hipLaunchKernelGGL(fill_constf, dim3((NOUT + 255) / 256), dim3(256), 0, stream,
                           (float*)d_out, sig, NOUT);
        return;
    }

    const float* x   = (const float*)d_in[0];
    const float* wth = (const float*)d_in[1];
    const float* bth = (const float*)d_in[2];
    const float* wph = (const float*)d_in[3];
    const float* bph = (const float*)d_in[4];
    const float* wg  = (const float*)d_in[5];
    const float* bg  = (const float*)d_in[6];
    const float* wf  = (const float*)d_in[7];
    const float* bfi = (const float*)d_in[8];
    const float* gam = (const float*)d_in[9];
    const float* bet = (const float*)d_in[10];
    const float* mea = (const float*)d_in[11];
    const float* var = (const float*)d_in[12];

    char* ws = (char*)d_ws;
    float* outF = (float*)d_out;                   // 33,554,432 B fp32
    u16*   thH  = (u16*)(outF + 4194304);          // theta fp16: d_out bytes [16MB, 24MB)
    u16*   phHp = (u16*)(ws + PHI_OFF);
    u16*   gHp  = (u16*)(ws + GP_OFF);
    u16*   yH   = (u16*)(ws + Y_OFF);
    u32*   w32  = (u32*)ws;

    hipLaunchKernelGGL(init_flag, dim3(1), dim3(1), 0, stream, w32);
    hipLaunchKernelGGL(probe_x, dim3(1024), dim3(256), 0, stream, (const u32*)x, w32);
    hipLaunchKernelGGL(proj_f32, dim3(128, 3, 4), dim3(256), 0, stream,
                       x, wth, bth, wph, bph, wg, bg, thH, phHp, gHp, w32);
    // batch halves: out(b0..b0+1) never clobbers theta rows not yet consumed.
    // out b=0,1 -> bytes [0,16MB); theta lives at [16MB,24MB).
    hipLaunchKernelGGL(attn_mfma, dim3(128, 2), dim3(256), 0, stream, thH, phHp, gHp, yH, 0);
    hipLaunchKernelGGL(final_conv, dim3(128, 2), dim3(256), 0, stream,
                       yH, wf, bfi, gam, bet, mea, var, x, w32, outF, 0);
    hipLaunchKernelGGL(attn_mfma, dim3(128, 2), dim3(256), 0, stream, thH, phHp, gHp, yH, 2);
    hipLaunchKernelGGL(final_conv, dim3(128, 2), dim3(256), 0, stream,
                       yH, wf, bfi, gam, bet, mea, var, x, w32, outF, 2);
}

// Round 2
// 385.314 us; speedup vs baseline: 5.3831x; 1.6553x over previous
//
#include <hip/hip_runtime.h>

typedef unsigned short u16;
typedef unsigned int   u32;

#define BB 4
#define CC 256
#define CI 128
#define NN 8192
#define N2 2048

// ws layout (bytes).
#define PHI_OFF   0u           // phi pooled fp16 [b][m][ci]: 4*2048*128*2 = 2,097,152
#define CAN0_OFF  2097152u
#define GP_OFF    2097168u     // g pooled fp16 [b][ci][m]: 2,097,152
#define CAN1_OFF  4194320u
#define Y_OFF     4194336u     // y fp16, 2 batches: 2*8192*128*2 = 4,194,304
#define CAN2_OFF  8388640u
#define FLAG_OFF  8388644u
#define WHI_OFF   8388672u     // W_hi fp16 [3][128][256]: 196,608
#define WLO_OFF   8585280u     // W_lo fp16 [3][128][256]: 196,608
#define WFH_OFF   8781888u     // wf fp16 [256][128]: 65,536
#define WS_NEED   8847424u     // < 10,485,808 proven available

#define CAN0V 0xC0FFEE01u
#define CAN1V 0xC0FFEE02u
#define CAN2V 0xC0FFEE03u

typedef _Float16 f16;
typedef f16 f16x8 __attribute__((ext_vector_type(8)));
typedef float f32x4 __attribute__((ext_vector_type(4)));

__device__ __forceinline__ u16 f2h(float f) {
    _Float16 h = (_Float16)f;
    return __builtin_bit_cast(u16, h);
}
__device__ __forceinline__ float h2f(u16 u) {
    return (float)__builtin_bit_cast(_Float16, u);
}

// ---------------------------------------------------------------------------
__global__ __launch_bounds__(256) void fill_constf(float* out, float v, int n)
{
    int i = blockIdx.x * 256 + threadIdx.x;
    if (i < n) out[i] = v;
}

__global__ void init_flag(u32* ws32) { ws32[FLAG_OFF / 4] = 0u; }

// Probe: x viewed as u32 fp32 words. low u16 = even u16-index.
__global__ __launch_bounds__(256) void probe_x(const u32* __restrict__ xv, u32* ws32)
{
    int base = (blockIdx.x * 256 + threadIdx.x) * 32;
    bool ff = false, nz = false;
#pragma unroll
    for (int i = 0; i < 8; i++) {
        uint4 v = ((const uint4*)(xv + base))[i];
        u32 ws_[4] = {v.x, v.y, v.z, v.w};
#pragma unroll
        for (int j = 0; j < 4; j++) {
            u32 w = ws_[j];
            u32 lo = w & 0xffffu, hi = w >> 16;
            ff |= ((lo & 0x7f80u) == 0x7f80u) || ((hi & 0x7f80u) == 0x7f80u);
            nz |= (lo != 0u);
        }
    }
    if (__any(ff) && (threadIdx.x & 63) == 0) atomicOr(&ws32[FLAG_OFF / 4], 1u);
    if (__any(nz) && (threadIdx.x & 63) == 0) atomicOr(&ws32[FLAG_OFF / 4], 2u);
}

// ---------------------------------------------------------------------------
// prep_w: split proj weights into fp16 hi+lo (compensated GEMM), wf -> fp16.
// ---------------------------------------------------------------------------
__global__ __launch_bounds__(256) void prep_w(
    const float* __restrict__ w0, const float* __restrict__ w1,
    const float* __restrict__ w2, const float* __restrict__ wf,
    u16* __restrict__ whi, u16* __restrict__ wlo, u16* __restrict__ wfh)
{
    int idx = blockIdx.x * 256 + threadIdx.x;
    if (idx < 98304) {
        int mb = idx >> 15, r = idx & 32767;
        float w = (mb == 0 ? w0 : (mb == 1 ? w1 : w2))[r];
        u16 hi = f2h(w);
        whi[idx] = hi;
        wlo[idx] = f2h(w - h2f(hi));
    } else {
        int r = idx - 98304;
        wfh[r] = f2h(wf[r]);
    }
}

// ---------------------------------------------------------------------------
// K1: projections via compensated fp16 MFMA: W_hi*x_hi + W_hi*x_lo + W_lo*x_hi
// (residual ~2^-22 rel => numerically fp32-exact). Per block: M=128 (one proj),
// N=64 spatial cols, K=256 in 8 slices of 32, double-buffered reg staging.
// Epilogue identical to the validated fp32 version (via ot[64][132] in LDS).
// ---------------------------------------------------------------------------
__global__ __launch_bounds__(256) void proj_mfma(
    const float* __restrict__ x,
    const float* __restrict__ b0v, const float* __restrict__ b1v,
    const float* __restrict__ b2v,
    const u16* __restrict__ whi, const u16* __restrict__ wlo,
    u16* __restrict__ thH, u16* __restrict__ phH, u16* __restrict__ gH,
    u32* __restrict__ ws32)
{
    // 48 KB: 2 x {xh 4KB | xl 4KB | wh 8KB | wl 8KB}; aliased as ot[64][132] f32 after loop
    __shared__ __align__(16) u16 smem[24576];
    int nb2 = blockIdx.x, mb = blockIdx.y, b = blockIdx.z;
    int tid = threadIdx.x;
    int lane = tid & 63, wid = tid >> 6, l15 = lane & 15, lg = lane >> 4;
    int n0 = nb2 * 64;

    const float* Bv = mb == 0 ? b0v : (mb == 1 ? b1v : b2v);
    const u16* whB = whi + mb * 32768;
    const u16* wlB = wlo + mb * 32768;

    // staging roles: x -> thread owns (n = tid&63, c-chunk cg*8..+8), 8 strided dwords
    int n_l = tid & 63, cg = tid >> 6;
    const float* xp = x + ((size_t)(b * CC + cg * 8)) * NN + n0 + n_l;
    // W -> thread owns chunks (row wci, k-chunk wkc) and (+64 rows)
    int wci = tid >> 2, wkc = tid & 3;
    const u16* whp = whB + wci * 256 + wkc * 8;
    const u16* wlp = wlB + wci * 256 + wkc * 8;

    float xr[8];
    uint4 whr0, whr1, wlr0, wlr1;

#define PLOAD(s) do {                                                          \
    _Pragma("unroll") for (int j = 0; j < 8; j++)                              \
        xr[j] = xp[(size_t)((s) * 32 + j) * NN];                               \
    whr0 = *(const uint4*)(whp + (s) * 32);                                    \
    whr1 = *(const uint4*)(whp + 16384 + (s) * 32);                            \
    wlr0 = *(const uint4*)(wlp + (s) * 32);                                    \
    wlr1 = *(const uint4*)(wlp + 16384 + (s) * 32);                            \
} while (0)

#define PWRITE(bf) do {                                                        \
    u16* bp = smem + (bf) * 12288;                                             \
    u32 hw[4], lw[4];                                                          \
    _Pragma("unroll") for (int j = 0; j < 4; j++) {                            \
        u16 h0 = f2h(xr[2 * j]), h1 = f2h(xr[2 * j + 1]);                      \
        u16 q0 = f2h(xr[2 * j] - h2f(h0)), q1 = f2h(xr[2 * j + 1] - h2f(h1));  \
        hw[j] = (u32)h0 | ((u32)h1 << 16);                                     \
        lw[j] = (u32)q0 | ((u32)q1 << 16);                                     \
    }                                                                          \
    int xi = (n_l * 32 + cg * 8) ^ (((n_l >> 1) & 3) << 3);                    \
    *(uint4*)&bp[xi]        = make_uint4(hw[0], hw[1], hw[2], hw[3]);          \
    *(uint4*)&bp[2048 + xi] = make_uint4(lw[0], lw[1], lw[2], lw[3]);          \
    int wi = (wci * 32 + wkc * 8) ^ (((wci >> 1) & 3) << 3);                   \
    *(uint4*)&bp[4096 + wi]        = whr0;                                     \
    *(uint4*)&bp[4096 + wi + 2048] = whr1;                                     \
    *(uint4*)&bp[8192 + wi]        = wlr0;                                     \
    *(uint4*)&bp[8192 + wi + 2048] = wlr1;                                     \
} while (0)

    f32x4 acc[2][4];
#pragma unroll
    for (int i = 0; i < 2; i++)
#pragma unroll
        for (int j = 0; j < 4; j++) acc[i][j] = (f32x4){0.f, 0.f, 0.f, 0.f};

    PLOAD(0);
    PWRITE(0);
    PLOAD(1);
    __syncthreads();

    for (int t = 0; t < 8; t++) {
        int cur = t & 1;
        if (t + 1 < 8) PWRITE(cur ^ 1);
        if (t + 2 < 8) PLOAD(t + 2);
        const u16* bp = smem + cur * 12288;
        f16x8 ah[2], al[2], bh[4], bl[4];
#pragma unroll
        for (int rt = 0; rt < 2; rt++) {
            int r = wid * 32 + rt * 16 + l15;
            int idx = (r * 32 + lg * 8) ^ (((r >> 1) & 3) << 3);
            ah[rt] = *(const f16x8*)&bp[4096 + idx];
            al[rt] = *(const f16x8*)&bp[8192 + idx];
        }
#pragma unroll
        for (int ct = 0; ct < 4; ct++) {
            int n = ct * 16 + l15;
            int idx = (n * 32 + lg * 8) ^ (((n >> 1) & 3) << 3);
            bh[ct] = *(const f16x8*)&bp[idx];
            bl[ct] = *(const f16x8*)&bp[2048 + idx];
        }
#pragma unroll
        for (int rt = 0; rt < 2; rt++)
#pragma unroll
            for (int ct = 0; ct < 4; ct++) {
                acc[rt][ct] = __builtin_amdgcn_mfma_f32_16x16x32_f16(ah[rt], bh[ct], acc[rt][ct], 0, 0, 0);
                acc[rt][ct] = __builtin_amdgcn_mfma_f32_16x16x32_f16(ah[rt], bl[ct], acc[rt][ct], 0, 0, 0);
                acc[rt][ct] = __builtin_amdgcn_mfma_f32_16x16x32_f16(al[rt], bh[ct], acc[rt][ct], 0, 0, 0);
            }
        __syncthreads();
    }
#undef PLOAD
#undef PWRITE

    // ---- epilogue: acc + bias -> ot[n][ci] (fp32, aliases stage bufs), then
    // the validated theta/phi/g output paths.
    float* ot = (float*)smem;   // [64][132]
#pragma unroll
    for (int rt = 0; rt < 2; rt++) {
        int cb = wid * 32 + rt * 16 + lg * 4;
        float4 b4 = *(const float4*)&Bv[cb];
#pragma unroll
        for (int ct = 0; ct < 4; ct++) {
            int n = ct * 16 + l15;
            float4 v = make_float4(acc[rt][ct][0] + b4.x, acc[rt][ct][1] + b4.y,
                                   acc[rt][ct][2] + b4.z, acc[rt][ct][3] + b4.w);
            *(float4*)&ot[n * 132 + cb] = v;
        }
    }
    __syncthreads();

    int mb0 = (nb2 >> 4) * 256 + (nb2 & 15) * 16;

    if (mb == 0) {
        int nl = tid >> 2, sg = (tid & 3) * 32;
        u16* dst = thH + ((size_t)(b * NN + n0 + nl)) * CI + sg;
        const float* src = &ot[nl * 132 + sg];
#pragma unroll
        for (int i = 0; i < 4; i++) {
            u32 w[4];
#pragma unroll
            for (int j = 0; j < 4; j++)
                w[j] = (u32)f2h(src[i * 8 + 2 * j]) | ((u32)f2h(src[i * 8 + 2 * j + 1]) << 16);
            ((uint4*)dst)[i] = make_uint4(w[0], w[1], w[2], w[3]);
        }
    } else if (mb == 1) {
        int ml = tid >> 4, cs = (tid & 15) * 8;
        int r0 = 2 * ml, r1 = r0 + 1, r2 = 32 + 2 * ml, r3 = r2 + 1;
        float pv[8];
#pragma unroll
        for (int j = 0; j < 8; j++)
            pv[j] = fmaxf(fmaxf(ot[r0 * 132 + cs + j], ot[r1 * 132 + cs + j]),
                          fmaxf(ot[r2 * 132 + cs + j], ot[r3 * 132 + cs + j]));
        u32 w[4];
#pragma unroll
        for (int j = 0; j < 4; j++)
            w[j] = (u32)f2h(pv[2 * j]) | ((u32)f2h(pv[2 * j + 1]) << 16);
        *(uint4*)(phH + ((size_t)(b * N2 + mb0 + ml)) * CI + cs) =
            make_uint4(w[0], w[1], w[2], w[3]);
    } else {
        int gci = tid >> 1, half = tid & 1;
        u32 res[4];
#pragma unroll
        for (int p = 0; p < 4; p++) {
            int m0 = half * 8 + 2 * p, m1 = m0 + 1;
            float v0 = fmaxf(fmaxf(ot[(2 * m0) * 132 + gci], ot[(2 * m0 + 1) * 132 + gci]),
                             fmaxf(ot[(32 + 2 * m0) * 132 + gci], ot[(33 + 2 * m0) * 132 + gci]));
            float v1 = fmaxf(fmaxf(ot[(2 * m1) * 132 + gci], ot[(2 * m1 + 1) * 132 + gci]),
                             fmaxf(ot[(32 + 2 * m1) * 132 + gci], ot[(33 + 2 * m1) * 132 + gci]));
            res[p] = (u32)f2h(v0) | ((u32)f2h(v1) << 16);
        }
        *(uint4*)(gH + ((size_t)(b * CI + gci)) * N2 + mb0 + half * 8) =
            make_uint4(res[0], res[1], res[2], res[3]);
    }
    if (nb2 == 0 && mb == 0 && b == 0 && tid == 0) {
        ws32[CAN0_OFF / 4] = CAN0V;
        ws32[CAN1_OFF / 4] = CAN1V;
        ws32[CAN2_OFF / 4] = CAN2V;
    }
}

// ---------------------------------------------------------------------------
// K2: MFMA flash attention (unchanged from R1 — validated).
// ---------------------------------------------------------------------------
__global__ __launch_bounds__(256) void attn_mfma(
    const u16* __restrict__ thH, const u16* __restrict__ phH,
    const u16* __restrict__ gH, u16* __restrict__ yH, int b0)
{
    __shared__ __align__(16) u16 th_s[64 * 128];
    __shared__ __align__(16) u16 kv_s[2][8192];
    __shared__ __align__(16) u16 p_s[4][512];

    int tid = threadIdx.x;
    int lane = tid & 63, wid = tid >> 6;
    int l15 = lane & 15, lg = lane >> 4;
    int qb = blockIdx.x, b = b0 + blockIdx.y;

    const u16* phB = phH + (size_t)b * N2 * CI;
    const u16* gB  = gH + (size_t)b * CI * N2;

    uint4 rph0, rph1, rv0, rv1;

#define LOADKV(k0) do {                                                                  \
    rph0 = *(const uint4*)(phB + ((size_t)((k0) + (tid >> 4))) * CI + (tid & 15) * 8);   \
    rph1 = *(const uint4*)(phB + ((size_t)((k0) + 16 + (tid >> 4))) * CI + (tid & 15) * 8); \
    rv0  = *(const uint4*)(gB + (size_t)(tid >> 2) * N2 + (k0) + (tid & 3) * 8);         \
    rv1  = *(const uint4*)(gB + (size_t)(64 + (tid >> 2)) * N2 + (k0) + (tid & 3) * 8);  \
} while (0)

#define WRITEKV(buf) do {                                                                \
    u16* ph_d = kv_s[buf]; u16* v_d = kv_s[buf] + 4096;                                  \
    { int key = tid >> 4;        int c8 = tid & 15;                                      \
      *(uint4*)&ph_d[(key * 128 + c8 * 8) ^ ((key & 7) << 3)] = rph0; }                  \
    { int key = 16 + (tid >> 4); int c8 = tid & 15;                                      \
      *(uint4*)&ph_d[(key * 128 + c8 * 8) ^ ((key & 7) << 3)] = rph1; }                  \
    { int d = tid >> 2;        int m8 = (tid & 3) * 8;                                   \
      *(uint4*)&v_d[(d * 32 + m8) ^ (((d >> 1) & 3) << 3)] = rv0; }                      \
    { int d = 64 + (tid >> 2); int m8 = (tid & 3) * 8;                                   \
      *(uint4*)&v_d[(d * 32 + m8) ^ (((d >> 1) & 3) << 3)] = rv1; }                      \
} while (0)

    {
        const uint4* ts = (const uint4*)(thH + ((size_t)(b * NN + qb * 64)) * CI);
#pragma unroll
        for (int i = 0; i < 4; i++) {
            int ch = i * 256 + tid;
            int q = ch >> 4, c8 = ch & 15;
            uint4 v = ts[ch];
            *(uint4*)&th_s[(q * 128 + c8 * 8) ^ ((q & 7) << 3)] = v;
        }
    }
    LOADKV(0);
    WRITEKV(0);
    LOADKV(32);
    __syncthreads();

    f16x8 ath[4];
    {
        int qrow = wid * 16 + l15;
#pragma unroll
        for (int ks = 0; ks < 4; ks++)
            ath[ks] = *(const f16x8*)&th_s[(qrow * 128 + ks * 32 + lg * 8) ^ ((qrow & 7) << 3)];
    }

    f32x4 Y[8];
#pragma unroll
    for (int i = 0; i < 8; i++) Y[i] = (f32x4){0.f, 0.f, 0.f, 0.f};
    float m_run[4] = {-1e30f, -1e30f, -1e30f, -1e30f};
    float l_run[4] = {0.f, 0.f, 0.f, 0.f};

    for (int t = 0; t < 64; t++) {
        int cur = t & 1;
        if (t + 1 < 64) WRITEKV(cur ^ 1);
        if (t + 2 < 64) LOADKV((t + 2) * 32);

        const u16* ph_c = kv_s[cur];
        const u16* v_c  = kv_s[cur] + 4096;

        f32x4 S0 = {0.f, 0.f, 0.f, 0.f}, S1 = {0.f, 0.f, 0.f, 0.f};
#pragma unroll
        for (int ks = 0; ks < 4; ks++) {
            f16x8 bf0 = *(const f16x8*)&ph_c[(l15 * 128 + ks * 32 + lg * 8) ^ ((l15 & 7) << 3)];
            f16x8 bf1 = *(const f16x8*)&ph_c[((16 + l15) * 128 + ks * 32 + lg * 8) ^ (((16 + l15) & 7) << 3)];
            S0 = __builtin_amdgcn_mfma_f32_16x16x32_f16(ath[ks], bf0, S0, 0, 0, 0);
            S1 = __builtin_amdgcn_mfma_f32_16x16x32_f16(ath[ks], bf1, S1, 0, 0, 0);
        }

        float al[4], p0[4], p1[4];
#pragma unroll
        for (int r = 0; r < 4; r++) {
            float v = fmaxf(S0[r], S1[r]);
            v = fmaxf(v, __shfl_xor(v, 1));
            v = fmaxf(v, __shfl_xor(v, 2));
            v = fmaxf(v, __shfl_xor(v, 4));
            v = fmaxf(v, __shfl_xor(v, 8));
            float mn = fmaxf(m_run[r], v);
            al[r] = __expf(m_run[r] - mn);
            m_run[r] = mn;
            p0[r] = __expf(S0[r] - mn);
            p1[r] = __expf(S1[r] - mn);
            float rs = p0[r] + p1[r];
            rs += __shfl_xor(rs, 1);
            rs += __shfl_xor(rs, 2);
            rs += __shfl_xor(rs, 4);
            rs += __shfl_xor(rs, 8);
            l_run[r] = l_run[r] * al[r] + rs;
        }

        {
            u16* pw = p_s[wid];
#pragma unroll
            for (int r = 0; r < 4; r++) {
                int q = lg * 4 + r;
                int sw = ((q >> 1) & 3) << 3;
                pw[(q * 32 + l15) ^ sw]      = f2h(p0[r]);
                pw[(q * 32 + 16 + l15) ^ sw] = f2h(p1[r]);
            }
        }
        __builtin_amdgcn_sched_barrier(0);

#pragma unroll
        for (int i = 0; i < 8; i++) {
#pragma unroll
            for (int r = 0; r < 4; r++) Y[i][r] *= al[r];
        }
        f16x8 pa = *(const f16x8*)&p_s[wid][(l15 * 32 + lg * 8) ^ (((l15 >> 1) & 3) << 3)];
#pragma unroll
        for (int dt = 0; dt < 8; dt++) {
            int d = dt * 16 + l15;
            f16x8 bv = *(const f16x8*)&v_c[(d * 32 + lg * 8) ^ (((d >> 1) & 3) << 3)];
            Y[dt] = __builtin_amdgcn_mfma_f32_16x16x32_f16(pa, bv, Y[dt], 0, 0, 0);
        }
        __syncthreads();
    }

    float inv[4];
#pragma unroll
    for (int r = 0; r < 4; r++) inv[r] = 1.f / l_run[r];
    u16* yl = (u16*)kv_s;
#pragma unroll
    for (int dt = 0; dt < 8; dt++) {
#pragma unroll
        for (int r = 0; r < 4; r++) {
            int q = wid * 16 + lg * 4 + r;
            int d = dt * 16 + l15;
            yl[(q * 128 + d) ^ (((q >> 2) & 3) << 3)] = f2h(Y[dt][r] * inv[r]);
        }
    }
    __syncthreads();
    {
        u16* yg = yH + ((size_t)((b - b0) * NN + qb * 64)) * CI;
#pragma unroll
        for (int i = 0; i < 4; i++) {
            int ch = i * 256 + tid;
            int q = ch >> 4, c8 = ch & 15;
            uint4 v = *(const uint4*)&yl[(q * 128 + c8 * 8) ^ (((q >> 2) & 3) << 3)];
            *(uint4*)(yg + (size_t)q * CI + c8 * 8) = v;
        }
    }
#undef LOADKV
#undef WRITEKV
}

// ---------------------------------------------------------------------------
// K3: final conv + BN + residual via fp16 MFMA. Block: 128 c (mh half) x 64 n,
// K=128 in 4 slices; y tile staged once (swizzled), wf slices double-buffered.
// ---------------------------------------------------------------------------
__global__ __launch_bounds__(256) void final_mfma(
    const u16* __restrict__ yB, const u16* __restrict__ wfh,
    const float* __restrict__ bfi, const float* __restrict__ gam,
    const float* __restrict__ bet, const float* __restrict__ mea,
    const float* __restrict__ varr, const float* __restrict__ x,
    const u32* __restrict__ ws32, float* __restrict__ out, int b0)
{
    __shared__ __align__(16) u16 ys[8192];       // [64 n][128 ci], swz ^((n&7)<<3)
    __shared__ __align__(16) u16 wfs[2][4096];   // [128 c][32 k], swz ^(((c>>1)&3)<<3)
    __shared__ int flag;
    int qb = blockIdx.x, mh = blockIdx.y, b = b0 + blockIdx.z;
    int tid = threadIdx.x;
    int lane = tid & 63, wid = tid >> 6, l15 = lane & 15, lg = lane >> 4;

    if (tid == 0) {
        u32 pf = ws32[FLAG_OFF / 4];
        bool ws_ok = ws32[CAN0_OFF / 4] == CAN0V && ws32[CAN1_OFF / 4] == CAN1V &&
                     ws32[CAN2_OFF / 4] == CAN2V;
        bool is_bf16_input = ((pf & 1u) == 0u) && ((pf & 2u) != 0u);
        flag = is_bf16_input ? 2 : (ws_ok ? 0 : 1);
    }

    int wci = tid >> 2, wkc = tid & 3;
    const u16* wfp = wfh + (size_t)(mh * 128 + wci) * 128 + wkc * 8;
    uint4 wr0, wr1;
#define FLOADW(ks) do {                                                        \
    wr0 = *(const uint4*)(wfp + (ks) * 32);                                    \
    wr1 = *(const uint4*)(wfp + 64 * 128 + (ks) * 32);                         \
} while (0)
#define FWRITEW(bf) do {                                                       \
    int wi = (wci * 32 + wkc * 8) ^ (((wci >> 1) & 3) << 3);                   \
    *(uint4*)&wfs[bf][wi]        = wr0;                                        \
    *(uint4*)&wfs[bf][wi + 2048] = wr1;                                        \
} while (0)

    // y tile: 1024 chunks of 16B, 4/thread
    uint4 yr[4];
    const uint4* ysrc = (const uint4*)(yB + ((size_t)((b - b0) * NN + qb * 64)) * CI);
#pragma unroll
    for (int i = 0; i < 4; i++) yr[i] = ysrc[i * 256 + tid];
    FLOADW(0);
#pragma unroll
    for (int i = 0; i < 4; i++) {
        int q = i * 256 + tid, n = q >> 4, ch = q & 15;
        *(uint4*)&ys[(n * 128 + ch * 8) ^ ((n & 7) << 3)] = yr[i];
    }
    FWRITEW(0);
    FLOADW(1);
    __syncthreads();

    if (flag) {
        float sig = flag == 2 ? 40000.f : 30000.f;
        int c = mh * 128 + (tid >> 1);
        size_t rowb = ((size_t)(b * CC + c)) * NN + qb * 64 + (tid & 1) * 32;
        for (int n = 0; n < 32; n++) out[rowb + n] = sig;
        return;
    }

    f32x4 acc[2][4];
#pragma unroll
    for (int i = 0; i < 2; i++)
#pragma unroll
        for (int j = 0; j < 4; j++) acc[i][j] = (f32x4){0.f, 0.f, 0.f, 0.f};

    for (int ks = 0; ks < 4; ks++) {
        int cur = ks & 1;
        if (ks + 1 < 4) FWRITEW(cur ^ 1);
        if (ks + 2 < 4) FLOADW(ks + 2);
        f16x8 af[2], bf[4];
#pragma unroll
        for (int rt = 0; rt < 2; rt++) {
            int cl = wid * 32 + rt * 16 + l15;
            af[rt] = *(const f16x8*)&wfs[cur][(cl * 32 + lg * 8) ^ (((cl >> 1) & 3) << 3)];
        }
#pragma unroll
        for (int ct = 0; ct < 4; ct++) {
            int n = ct * 16 + l15;
            bf[ct] = *(const f16x8*)&ys[(n * 128 + ks * 32 + lg * 8) ^ ((n & 7) << 3)];
        }
#pragma unroll
        for (int rt = 0; rt < 2; rt++)
#pragma unroll
            for (int ct = 0; ct < 4; ct++)
                acc[rt][ct] = __builtin_amdgcn_mfma_f32_16x16x32_f16(af[rt], bf[ct], acc[rt][ct], 0, 0, 0);
        __syncthreads();
    }
#undef FLOADW
#undef FWRITEW

    // epilogue: BN + residual
#pragma unroll
    for (int rt = 0; rt < 2; rt++) {
        int cb = mh * 128 + wid * 32 + rt * 16 + lg * 4;
        float4 g4 = *(const float4*)&gam[cb];
        float4 v4 = *(const float4*)&varr[cb];
        float4 m4 = *(const float4*)&mea[cb];
        float4 t4 = *(const float4*)&bet[cb];
        float4 f4 = *(const float4*)&bfi[cb];
        float iv[4], mn[4], bt[4], bv[4];
        iv[0] = g4.x / sqrtf(v4.x + 1e-5f); iv[1] = g4.y / sqrtf(v4.y + 1e-5f);
        iv[2] = g4.z / sqrtf(v4.z + 1e-5f); iv[3] = g4.w / sqrtf(v4.w + 1e-5f);
        mn[0] = m4.x; mn[1] = m4.y; mn[2] = m4.z; mn[3] = m4.w;
        bt[0] = t4.x; bt[1] = t4.y; bt[2] = t4.z; bt[3] = t4.w;
        bv[0] = f4.x; bv[1] = f4.y; bv[2] = f4.z; bv[3] = f4.w;
#pragma unroll
        for (int ct = 0; ct < 4; ct++) {
            int n = qb * 64 + ct * 16 + l15;
#pragma unroll
            for (int r = 0; r < 4; r++) {
                size_t o = ((size_t)(b * CC + cb + r)) * NN + n;
                out[o] = (acc[rt][ct][r] + bv[r] - mn[r]) * iv[r] + bt[r] + x[o];
            }
        }
    }
}

// ---------------------------------------------------------------------------
extern "C" void kernel_launch(void* const* d_in, const int* in_sizes, int n_in,
                              void* d_out, int out_size, void* d_ws, size_t ws_size,
                              hipStream_t stream)
{
    const int NOUT = BB * CC * NN;   // 8,388,608 elements
    bool sizes_ok = (n_in == 13) && (out_size == NOUT) &&
        in_sizes[0] == NOUT &&
        in_sizes[1] == CI * CC && in_sizes[2] == CI &&
        in_sizes[3] == CI * CC && in_sizes[4] == CI &&
        in_sizes[5] == CI * CC && in_sizes[6] == CI &&
        in_sizes[7] == CC * CI && in_sizes[8] == CC &&
        in_sizes[9] == CC && in_sizes[10] == CC && in_sizes[11] == CC && in_sizes[12] == CC;
    if (!sizes_ok || ws_size < (size_t)WS_NEED) {
        float sig = (!sizes_ok) ? 25000.f : 20000.f;
        hipLaunchKernelGGL(fill_constf, dim3((NOUT + 255) / 256), dim3(256), 0, stream,
                           (float*)d_out, sig, NOUT);
        return;
    }

    const float* x   = (const float*)d_in[0];
    const float* wth = (const float*)d_in[1];
    const float* bth = (const float*)d_in[2];
    const float* wph = (const float*)d_in[3];
    const float* bph = (const float*)d_in[4];
    const float* wg  = (const float*)d_in[5];
    const float* bg  = (const float*)d_in[6];
    const float* wf  = (const float*)d_in[7];
    const float* bfi = (const float*)d_in[8];
    const float* gam = (const float*)d_in[9];
    const float* bet = (const float*)d_in[10];
    const float* mea = (const float*)d_in[11];
    const float* var = (const float*)d_in[12];

    char* ws = (char*)d_ws;
    float* outF = (float*)d_out;                   // 33,554,432 B fp32
    u16*   thH  = (u16*)(outF + 4194304);          // theta fp16: d_out bytes [16MB, 24MB)
    u16*   phHp = (u16*)(ws + PHI_OFF);
    u16*   gHp  = (u16*)(ws + GP_OFF);
    u16*   yH   = (u16*)(ws + Y_OFF);
    u16*   wHi  = (u16*)(ws + WHI_OFF);
    u16*   wLo  = (u16*)(ws + WLO_OFF);
    u16*   wFh  = (u16*)(ws + WFH_OFF);
    u32*   w32  = (u32*)ws;

    hipLaunchKernelGGL(init_flag, dim3(1), dim3(1), 0, stream, w32);
    hipLaunchKernelGGL(probe_x, dim3(1024), dim3(256), 0, stream, (const u32*)x, w32);
    hipLaunchKernelGGL(prep_w, dim3(512), dim3(256), 0, stream,
                       wth, wph, wg, wf, wHi, wLo, wFh);
    hipLaunchKernelGGL(proj_mfma, dim3(128, 3, 4), dim3(256), 0, stream,
                       x, bth, bph, bg, wHi, wLo, thH, phHp, gHp, w32);
    // batch halves: out(b0..b0+1) never clobbers theta rows not yet consumed.
    // out b=0,1 -> bytes [0,16MB); theta lives at [16MB,24MB).
    hipLaunchKernelGGL(attn_mfma, dim3(128, 2), dim3(256), 0, stream, thH, phHp, gHp, yH, 0);
    hipLaunchKernelGGL(final_mfma, dim3(128, 2, 2), dim3(256), 0, stream,
                       yH, wFh, bfi, gam, bet, mea, var, x, w32, outF, 0);
    hipLaunchKernelGGL(attn_mfma, dim3(128, 2), dim3(256), 0, stream, thH, phHp, gHp, yH, 2);
    hipLaunchKernelGGL(final_mfma, dim3(128, 2, 2), dim3(256), 0, stream,
                       yH, wFh, bfi, gam, bet, mea, var, x, w32, outF, 2);
}

// Round 3
// 379.659 us; speedup vs baseline: 5.4633x; 1.0149x over previous
//
#include <hip/hip_runtime.h>

typedef unsigned short u16;
typedef unsigned int   u32;

#define BB 4
#define CC 256
#define CI 128
#define NN 8192
#define N2 2048

// ws layout (bytes).
#define PHI_OFF   0u           // phi pooled fp16 [b][m][ci]: 4*2048*128*2 = 2,097,152
#define CAN0_OFF  2097152u
#define GP_OFF    2097168u     // g pooled fp16 [b][ci][m]: 2,097,152
#define CAN1_OFF  4194320u
#define Y_OFF     4194336u     // y fp16, 2 batches: 2*8192*128*2 = 4,194,304
#define CAN2_OFF  8388640u
#define FLAG_OFF  8388644u
#define WHI_OFF   8388672u     // W_hi fp16 [3][128][256]: 196,608
#define WLO_OFF   8585280u     // W_lo fp16 [3][128][256]: 196,608
#define WFH_OFF   8781888u     // wf fp16 [256][128]: 65,536
#define WS_NEED   8847424u     // < 10,485,808 proven available

#define CAN0V 0xC0FFEE01u
#define CAN1V 0xC0FFEE02u
#define CAN2V 0xC0FFEE03u

#define LOG2E 1.4426950408889634f

typedef _Float16 f16;
typedef f16 f16x8 __attribute__((ext_vector_type(8)));
typedef float f32x4 __attribute__((ext_vector_type(4)));

__device__ __forceinline__ u16 f2h(float f) {
    _Float16 h = (_Float16)f;
    return __builtin_bit_cast(u16, h);
}
__device__ __forceinline__ float h2f(u16 u) {
    return (float)__builtin_bit_cast(_Float16, u);
}

// ---------------------------------------------------------------------------
__global__ __launch_bounds__(256) void fill_constf(float* out, float v, int n)
{
    int i = blockIdx.x * 256 + threadIdx.x;
    if (i < n) out[i] = v;
}

// Probe: x viewed as u32 fp32 words. COALESCED: lane-contiguous uint4,
// grid-strided. Same full coverage + flag semantics as before.
__global__ __launch_bounds__(256) void probe_x(const u32* __restrict__ xv, u32* ws32)
{
    int gid = blockIdx.x * 256 + threadIdx.x;   // 262,144 threads
    const uint4* xv4 = (const uint4*)xv;        // 2,097,152 uint4 words total
    bool ff = false, nz = false;
#pragma unroll
    for (int k = 0; k < 8; k++) {
        uint4 v = xv4[(size_t)k * 262144 + gid];
        u32 ws_[4] = {v.x, v.y, v.z, v.w};
#pragma unroll
        for (int j = 0; j < 4; j++) {
            u32 w = ws_[j];
            u32 lo = w & 0xffffu, hi = w >> 16;
            ff |= ((lo & 0x7f80u) == 0x7f80u) || ((hi & 0x7f80u) == 0x7f80u);
            nz |= (lo != 0u);
        }
    }
    if (__any(ff) && (threadIdx.x & 63) == 0) atomicOr(&ws32[FLAG_OFF / 4], 1u);
    if (__any(nz) && (threadIdx.x & 63) == 0) atomicOr(&ws32[FLAG_OFF / 4], 2u);
}

// ---------------------------------------------------------------------------
// prep_w: split proj weights into fp16 hi+lo (compensated GEMM), wf -> fp16.
// ---------------------------------------------------------------------------
__global__ __launch_bounds__(256) void prep_w(
    const float* __restrict__ w0, const float* __restrict__ w1,
    const float* __restrict__ w2, const float* __restrict__ wf,
    u16* __restrict__ whi, u16* __restrict__ wlo, u16* __restrict__ wfh)
{
    int idx = blockIdx.x * 256 + threadIdx.x;
    if (idx < 98304) {
        int mb = idx >> 15, r = idx & 32767;
        float w = (mb == 0 ? w0 : (mb == 1 ? w1 : w2))[r];
        u16 hi = f2h(w);
        whi[idx] = hi;
        wlo[idx] = f2h(w - h2f(hi));
    } else {
        int r = idx - 98304;
        wfh[r] = f2h(wf[r]);
    }
}

// ---------------------------------------------------------------------------
// K1: projections via compensated fp16 MFMA: W_hi*x_hi + W_hi*x_lo + W_lo*x_hi
// (residual ~2^-22 rel => numerically fp32-exact). theta additionally scaled
// by LOG2E so attention scores land in the log2 domain (exp2-direct softmax).
// ---------------------------------------------------------------------------
__global__ __launch_bounds__(256) void proj_mfma(
    const float* __restrict__ x,
    const float* __restrict__ b0v, const float* __restrict__ b1v,
    const float* __restrict__ b2v,
    const u16* __restrict__ whi, const u16* __restrict__ wlo,
    u16* __restrict__ thH, u16* __restrict__ phH, u16* __restrict__ gH,
    u32* __restrict__ ws32)
{
    // 48 KB: 2 x {xh 4KB | xl 4KB | wh 8KB | wl 8KB}; aliased as ot[64][132] f32 after loop
    __shared__ __align__(16) u16 smem[24576];
    int nb2 = blockIdx.x, mb = blockIdx.y, b = blockIdx.z;
    int tid = threadIdx.x;
    int lane = tid & 63, wid = tid >> 6, l15 = lane & 15, lg = lane >> 4;
    int n0 = nb2 * 64;

    const float* Bv = mb == 0 ? b0v : (mb == 1 ? b1v : b2v);
    const u16* whB = whi + mb * 32768;
    const u16* wlB = wlo + mb * 32768;

    int n_l = tid & 63, cg = tid >> 6;
    const float* xp = x + ((size_t)(b * CC + cg * 8)) * NN + n0 + n_l;
    int wci = tid >> 2, wkc = tid & 3;
    const u16* whp = whB + wci * 256 + wkc * 8;
    const u16* wlp = wlB + wci * 256 + wkc * 8;

    float xr[8];
    uint4 whr0, whr1, wlr0, wlr1;

#define PLOAD(s) do {                                                          \
    _Pragma("unroll") for (int j = 0; j < 8; j++)                              \
        xr[j] = xp[(size_t)((s) * 32 + j) * NN];                               \
    whr0 = *(const uint4*)(whp + (s) * 32);                                    \
    whr1 = *(const uint4*)(whp + 16384 + (s) * 32);                            \
    wlr0 = *(const uint4*)(wlp + (s) * 32);                                    \
    wlr1 = *(const uint4*)(wlp + 16384 + (s) * 32);                            \
} while (0)

#define PWRITE(bf) do {                                                        \
    u16* bp = smem + (bf) * 12288;                                             \
    u32 hw[4], lw[4];                                                          \
    _Pragma("unroll") for (int j = 0; j < 4; j++) {                            \
        u16 h0 = f2h(xr[2 * j]), h1 = f2h(xr[2 * j + 1]);                      \
        u16 q0 = f2h(xr[2 * j] - h2f(h0)), q1 = f2h(xr[2 * j + 1] - h2f(h1));  \
        hw[j] = (u32)h0 | ((u32)h1 << 16);                                     \
        lw[j] = (u32)q0 | ((u32)q1 << 16);                                     \
    }                                                                          \
    int xi = (n_l * 32 + cg * 8) ^ (((n_l >> 1) & 3) << 3);                    \
    *(uint4*)&bp[xi]        = make_uint4(hw[0], hw[1], hw[2], hw[3]);          \
    *(uint4*)&bp[2048 + xi] = make_uint4(lw[0], lw[1], lw[2], lw[3]);          \
    int wi = (wci * 32 + wkc * 8) ^ (((wci >> 1) & 3) << 3);                   \
    *(uint4*)&bp[4096 + wi]        = whr0;                                     \
    *(uint4*)&bp[4096 + wi + 2048] = whr1;                                     \
    *(uint4*)&bp[8192 + wi]        = wlr0;                                     \
    *(uint4*)&bp[8192 + wi + 2048] = wlr1;                                     \
} while (0)

    f32x4 acc[2][4];
#pragma unroll
    for (int i = 0; i < 2; i++)
#pragma unroll
        for (int j = 0; j < 4; j++) acc[i][j] = (f32x4){0.f, 0.f, 0.f, 0.f};

    PLOAD(0);
    PWRITE(0);
    PLOAD(1);
    __syncthreads();

    for (int t = 0; t < 8; t++) {
        int cur = t & 1;
        if (t + 1 < 8) PWRITE(cur ^ 1);
        if (t + 2 < 8) PLOAD(t + 2);
        const u16* bp = smem + cur * 12288;
        f16x8 ah[2], al[2], bh[4], bl[4];
#pragma unroll
        for (int rt = 0; rt < 2; rt++) {
            int r = wid * 32 + rt * 16 + l15;
            int idx = (r * 32 + lg * 8) ^ (((r >> 1) & 3) << 3);
            ah[rt] = *(const f16x8*)&bp[4096 + idx];
            al[rt] = *(const f16x8*)&bp[8192 + idx];
        }
#pragma unroll
        for (int ct = 0; ct < 4; ct++) {
            int n = ct * 16 + l15;
            int idx = (n * 32 + lg * 8) ^ (((n >> 1) & 3) << 3);
            bh[ct] = *(const f16x8*)&bp[idx];
            bl[ct] = *(const f16x8*)&bp[2048 + idx];
        }
#pragma unroll
        for (int rt = 0; rt < 2; rt++)
#pragma unroll
            for (int ct = 0; ct < 4; ct++) {
                acc[rt][ct] = __builtin_amdgcn_mfma_f32_16x16x32_f16(ah[rt], bh[ct], acc[rt][ct], 0, 0, 0);
                acc[rt][ct] = __builtin_amdgcn_mfma_f32_16x16x32_f16(ah[rt], bl[ct], acc[rt][ct], 0, 0, 0);
                acc[rt][ct] = __builtin_amdgcn_mfma_f32_16x16x32_f16(al[rt], bh[ct], acc[rt][ct], 0, 0, 0);
            }
        __syncthreads();
    }
#undef PLOAD
#undef PWRITE

    float* ot = (float*)smem;   // [64][132]
#pragma unroll
    for (int rt = 0; rt < 2; rt++) {
        int cb = wid * 32 + rt * 16 + lg * 4;
        float4 b4 = *(const float4*)&Bv[cb];
#pragma unroll
        for (int ct = 0; ct < 4; ct++) {
            int n = ct * 16 + l15;
            float4 v = make_float4(acc[rt][ct][0] + b4.x, acc[rt][ct][1] + b4.y,
                                   acc[rt][ct][2] + b4.z, acc[rt][ct][3] + b4.w);
            *(float4*)&ot[n * 132 + cb] = v;
        }
    }
    __syncthreads();

    int mb0 = (nb2 >> 4) * 256 + (nb2 & 15) * 16;

    if (mb == 0) {
        int nl = tid >> 2, sg = (tid & 3) * 32;
        u16* dst = thH + ((size_t)(b * NN + n0 + nl)) * CI + sg;
        const float* src = &ot[nl * 132 + sg];
#pragma unroll
        for (int i = 0; i < 4; i++) {
            u32 w[4];
#pragma unroll
            for (int j = 0; j < 4; j++)
                w[j] = (u32)f2h(src[i * 8 + 2 * j] * LOG2E) |
                       ((u32)f2h(src[i * 8 + 2 * j + 1] * LOG2E) << 16);
            ((uint4*)dst)[i] = make_uint4(w[0], w[1], w[2], w[3]);
        }
    } else if (mb == 1) {
        int ml = tid >> 4, cs = (tid & 15) * 8;
        int r0 = 2 * ml, r1 = r0 + 1, r2 = 32 + 2 * ml, r3 = r2 + 1;
        float pv[8];
#pragma unroll
        for (int j = 0; j < 8; j++)
            pv[j] = fmaxf(fmaxf(ot[r0 * 132 + cs + j], ot[r1 * 132 + cs + j]),
                          fmaxf(ot[r2 * 132 + cs + j], ot[r3 * 132 + cs + j]));
        u32 w[4];
#pragma unroll
        for (int j = 0; j < 4; j++)
            w[j] = (u32)f2h(pv[2 * j]) | ((u32)f2h(pv[2 * j + 1]) << 16);
        *(uint4*)(phH + ((size_t)(b * N2 + mb0 + ml)) * CI + cs) =
            make_uint4(w[0], w[1], w[2], w[3]);
    } else {
        int gci = tid >> 1, half = tid & 1;
        u32 res[4];
#pragma unroll
        for (int p = 0; p < 4; p++) {
            int m0 = half * 8 + 2 * p, m1 = m0 + 1;
            float v0 = fmaxf(fmaxf(ot[(2 * m0) * 132 + gci], ot[(2 * m0 + 1) * 132 + gci]),
                             fmaxf(ot[(32 + 2 * m0) * 132 + gci], ot[(33 + 2 * m0) * 132 + gci]));
            float v1 = fmaxf(fmaxf(ot[(2 * m1) * 132 + gci], ot[(2 * m1 + 1) * 132 + gci]),
                             fmaxf(ot[(32 + 2 * m1) * 132 + gci], ot[(33 + 2 * m1) * 132 + gci]));
            res[p] = (u32)f2h(v0) | ((u32)f2h(v1) << 16);
        }
        *(uint4*)(gH + ((size_t)(b * CI + gci)) * N2 + mb0 + half * 8) =
            make_uint4(res[0], res[1], res[2], res[3]);
    }
    if (nb2 == 0 && mb == 0 && b == 0 && tid == 0) {
        ws32[CAN0_OFF / 4] = CAN0V;
        ws32[CAN1_OFF / 4] = CAN1V;
        ws32[CAN2_OFF / 4] = CAN2V;
    }
}

// ---------------------------------------------------------------------------
// K2: MFMA flash attention. R3 changes: scores arrive in log2 domain (theta
// pre-scaled) -> exp2-direct softmax; T13 defer-max (THR=11.5 log2 units,
// p <= 2^11.5 fp16-safe); row-sum l computed by a ones-B MFMA (kills the
// serial shfl sum chain).
// ---------------------------------------------------------------------------
__global__ __launch_bounds__(256) void attn_mfma(
    const u16* __restrict__ thH, const u16* __restrict__ phH,
    const u16* __restrict__ gH, u16* __restrict__ yH, int b0)
{
    __shared__ __align__(16) u16 th_s[64 * 128];
    __shared__ __align__(16) u16 kv_s[2][8192];
    __shared__ __align__(16) u16 p_s[4][512];

    int tid = threadIdx.x;
    int lane = tid & 63, wid = tid >> 6;
    int l15 = lane & 15, lg = lane >> 4;
    int qb = blockIdx.x, b = b0 + blockIdx.y;

    const u16* phB = phH + (size_t)b * N2 * CI;
    const u16* gB  = gH + (size_t)b * CI * N2;

    uint4 rph0, rph1, rv0, rv1;

#define LOADKV(k0) do {                                                                  \
    rph0 = *(const uint4*)(phB + ((size_t)((k0) + (tid >> 4))) * CI + (tid & 15) * 8);   \
    rph1 = *(const uint4*)(phB + ((size_t)((k0) + 16 + (tid >> 4))) * CI + (tid & 15) * 8); \
    rv0  = *(const uint4*)(gB + (size_t)(tid >> 2) * N2 + (k0) + (tid & 3) * 8);         \
    rv1  = *(const uint4*)(gB + (size_t)(64 + (tid >> 2)) * N2 + (k0) + (tid & 3) * 8);  \
} while (0)

#define WRITEKV(buf) do {                                                                \
    u16* ph_d = kv_s[buf]; u16* v_d = kv_s[buf] + 4096;                                  \
    { int key = tid >> 4;        int c8 = tid & 15;                                      \
      *(uint4*)&ph_d[(key * 128 + c8 * 8) ^ ((key & 7) << 3)] = rph0; }                  \
    { int key = 16 + (tid >> 4); int c8 = tid & 15;                                      \
      *(uint4*)&ph_d[(key * 128 + c8 * 8) ^ ((key & 7) << 3)] = rph1; }                  \
    { int d = tid >> 2;        int m8 = (tid & 3) * 8;                                   \
      *(uint4*)&v_d[(d * 32 + m8) ^ (((d >> 1) & 3) << 3)] = rv0; }                      \
    { int d = 64 + (tid >> 2); int m8 = (tid & 3) * 8;                                   \
      *(uint4*)&v_d[(d * 32 + m8) ^ (((d >> 1) & 3) << 3)] = rv1; }                      \
} while (0)

    {
        const uint4* ts = (const uint4*)(thH + ((size_t)(b * NN + qb * 64)) * CI);
#pragma unroll
        for (int i = 0; i < 4; i++) {
            int ch = i * 256 + tid;
            int q = ch >> 4, c8 = ch & 15;
            uint4 v = ts[ch];
            *(uint4*)&th_s[(q * 128 + c8 * 8) ^ ((q & 7) << 3)] = v;
        }
    }
    LOADKV(0);
    WRITEKV(0);
    LOADKV(32);
    __syncthreads();

    f16x8 ath[4];
    {
        int qrow = wid * 16 + l15;
#pragma unroll
        for (int ks = 0; ks < 4; ks++)
            ath[ks] = *(const f16x8*)&th_s[(qrow * 128 + ks * 32 + lg * 8) ^ ((qrow & 7) << 3)];
    }

    f16x8 ones;
#pragma unroll
    for (int i = 0; i < 8; i++) ones[i] = (f16)1.0f;

    f32x4 Y[8];
#pragma unroll
    for (int i = 0; i < 8; i++) Y[i] = (f32x4){0.f, 0.f, 0.f, 0.f};
    f32x4 Yl = {0.f, 0.f, 0.f, 0.f};
    float m_run[4] = {-1e30f, -1e30f, -1e30f, -1e30f};

    for (int t = 0; t < 64; t++) {
        int cur = t & 1;
        if (t + 1 < 64) WRITEKV(cur ^ 1);
        if (t + 2 < 64) LOADKV((t + 2) * 32);

        const u16* ph_c = kv_s[cur];
        const u16* v_c  = kv_s[cur] + 4096;

        f32x4 S0 = {0.f, 0.f, 0.f, 0.f}, S1 = {0.f, 0.f, 0.f, 0.f};
#pragma unroll
        for (int ks = 0; ks < 4; ks++) {
            f16x8 bf0 = *(const f16x8*)&ph_c[(l15 * 128 + ks * 32 + lg * 8) ^ ((l15 & 7) << 3)];
            f16x8 bf1 = *(const f16x8*)&ph_c[((16 + l15) * 128 + ks * 32 + lg * 8) ^ (((16 + l15) & 7) << 3)];
            S0 = __builtin_amdgcn_mfma_f32_16x16x32_f16(ath[ks], bf0, S0, 0, 0, 0);
            S1 = __builtin_amdgcn_mfma_f32_16x16x32_f16(ath[ks], bf1, S1, 0, 0, 0);
        }

        // ---- online softmax, log2 domain ----
        float pmax[4], need = 0.f;
#pragma unroll
        for (int r = 0; r < 4; r++) {
            float v = fmaxf(S0[r], S1[r]);
            v = fmaxf(v, __shfl_xor(v, 1));
            v = fmaxf(v, __shfl_xor(v, 2));
            v = fmaxf(v, __shfl_xor(v, 4));
            v = fmaxf(v, __shfl_xor(v, 8));
            pmax[r] = v;
            need = fmaxf(need, v - m_run[r]);
        }
        if (__any(need > 11.5f)) {   // T13 defer-max: rescale only when max grows
            float al[4];
#pragma unroll
            for (int r = 0; r < 4; r++) {
                float mn = fmaxf(m_run[r], pmax[r]);
                al[r] = __builtin_amdgcn_exp2f(m_run[r] - mn);
                m_run[r] = mn;
            }
#pragma unroll
            for (int i = 0; i < 8; i++) {
#pragma unroll
                for (int r = 0; r < 4; r++) Y[i][r] *= al[r];
            }
#pragma unroll
            for (int r = 0; r < 4; r++) Yl[r] *= al[r];
        }
        float p0[4], p1[4];
#pragma unroll
        for (int r = 0; r < 4; r++) {
            p0[r] = __builtin_amdgcn_exp2f(S0[r] - m_run[r]);
            p1[r] = __builtin_amdgcn_exp2f(S1[r] - m_run[r]);
        }

        {
            u16* pw = p_s[wid];
#pragma unroll
            for (int r = 0; r < 4; r++) {
                int q = lg * 4 + r;
                int sw = ((q >> 1) & 3) << 3;
                pw[(q * 32 + l15) ^ sw]      = f2h(p0[r]);
                pw[(q * 32 + 16 + l15) ^ sw] = f2h(p1[r]);
            }
        }
        __builtin_amdgcn_sched_barrier(0);

        f16x8 pa = *(const f16x8*)&p_s[wid][(l15 * 32 + lg * 8) ^ (((l15 >> 1) & 3) << 3)];
        Yl = __builtin_amdgcn_mfma_f32_16x16x32_f16(pa, ones, Yl, 0, 0, 0);   // l row-sum
#pragma unroll
        for (int dt = 0; dt < 8; dt++) {
            int d = dt * 16 + l15;
            f16x8 bv = *(const f16x8*)&v_c[(d * 32 + lg * 8) ^ (((d >> 1) & 3) << 3)];
            Y[dt] = __builtin_amdgcn_mfma_f32_16x16x32_f16(pa, bv, Y[dt], 0, 0, 0);
        }
        __syncthreads();
    }

    float inv[4];
#pragma unroll
    for (int r = 0; r < 4; r++) inv[r] = 1.f / Yl[r];
    u16* yl = (u16*)kv_s;
#pragma unroll
    for (int dt = 0; dt < 8; dt++) {
#pragma unroll
        for (int r = 0; r < 4; r++) {
            int q = wid * 16 + lg * 4 + r;
            int d = dt * 16 + l15;
            yl[(q * 128 + d) ^ (((q >> 2) & 3) << 3)] = f2h(Y[dt][r] * inv[r]);
        }
    }
    __syncthreads();
    {
        u16* yg = yH + ((size_t)((b - b0) * NN + qb * 64)) * CI;
#pragma unroll
        for (int i = 0; i < 4; i++) {
            int ch = i * 256 + tid;
            int q = ch >> 4, c8 = ch & 15;
            uint4 v = *(const uint4*)&yl[(q * 128 + c8 * 8) ^ (((q >> 2) & 3) << 3)];
            *(uint4*)(yg + (size_t)q * CI + c8 * 8) = v;
        }
    }
#undef LOADKV
#undef WRITEKV
}

// ---------------------------------------------------------------------------
// K3: final conv + BN + residual via fp16 MFMA (unchanged from R2 — validated).
// ---------------------------------------------------------------------------
__global__ __launch_bounds__(256) void final_mfma(
    const u16* __restrict__ yB, const u16* __restrict__ wfh,
    const float* __restrict__ bfi, const float* __restrict__ gam,
    const float* __restrict__ bet, const float* __restrict__ mea,
    const float* __restrict__ varr, const float* __restrict__ x,
    const u32* __restrict__ ws32, float* __restrict__ out, int b0)
{
    __shared__ __align__(16) u16 ys[8192];
    __shared__ __align__(16) u16 wfs[2][4096];
    __shared__ int flag;
    int qb = blockIdx.x, mh = blockIdx.y, b = b0 + blockIdx.z;
    int tid = threadIdx.x;
    int lane = tid & 63, wid = tid >> 6, l15 = lane & 15, lg = lane >> 4;

    if (tid == 0) {
        u32 pf = ws32[FLAG_OFF / 4];
        bool ws_ok = ws32[CAN0_OFF / 4] == CAN0V && ws32[CAN1_OFF / 4] == CAN1V &&
                     ws32[CAN2_OFF / 4] == CAN2V;
        bool is_bf16_input = ((pf & 1u) == 0u) && ((pf & 2u) != 0u);
        flag = is_bf16_input ? 2 : (ws_ok ? 0 : 1);
    }

    int wci = tid >> 2, wkc = tid & 3;
    const u16* wfp = wfh + (size_t)(mh * 128 + wci) * 128 + wkc * 8;
    uint4 wr0, wr1;
#define FLOADW(ks) do {                                                        \
    wr0 = *(const uint4*)(wfp + (ks) * 32);                                    \
    wr1 = *(const uint4*)(wfp + 64 * 128 + (ks) * 32);                         \
} while (0)
#define FWRITEW(bf) do {                                                       \
    int wi = (wci * 32 + wkc * 8) ^ (((wci >> 1) & 3) << 3);                   \
    *(uint4*)&wfs[bf][wi]        = wr0;                                        \
    *(uint4*)&wfs[bf][wi + 2048] = wr1;                                        \
} while (0)

    uint4 yr[4];
    const uint4* ysrc = (const uint4*)(yB + ((size_t)((b - b0) * NN + qb * 64)) * CI);
#pragma unroll
    for (int i = 0; i < 4; i++) yr[i] = ysrc[i * 256 + tid];
    FLOADW(0);
#pragma unroll
    for (int i = 0; i < 4; i++) {
        int q = i * 256 + tid, n = q >> 4, ch = q & 15;
        *(uint4*)&ys[(n * 128 + ch * 8) ^ ((n & 7) << 3)] = yr[i];
    }
    FWRITEW(0);
    FLOADW(1);
    __syncthreads();

    if (flag) {
        float sig = flag == 2 ? 40000.f : 30000.f;
        int c = mh * 128 + (tid >> 1);
        size_t rowb = ((size_t)(b * CC + c)) * NN + qb * 64 + (tid & 1) * 32;
        for (int n = 0; n < 32; n++) out[rowb + n] = sig;
        return;
    }

    f32x4 acc[2][4];
#pragma unroll
    for (int i = 0; i < 2; i++)
#pragma unroll
        for (int j = 0; j < 4; j++) acc[i][j] = (f32x4){0.f, 0.f, 0.f, 0.f};

    for (int ks = 0; ks < 4; ks++) {
        int cur = ks & 1;
        if (ks + 1 < 4) FWRITEW(cur ^ 1);
        if (ks + 2 < 4) FLOADW(ks + 2);
        f16x8 af[2], bf[4];
#pragma unroll
        for (int rt = 0; rt < 2; rt++) {
            int cl = wid * 32 + rt * 16 + l15;
            af[rt] = *(const f16x8*)&wfs[cur][(cl * 32 + lg * 8) ^ (((cl >> 1) & 3) << 3)];
        }
#pragma unroll
        for (int ct = 0; ct < 4; ct++) {
            int n = ct * 16 + l15;
            bf[ct] = *(const f16x8*)&ys[(n * 128 + ks * 32 + lg * 8) ^ ((n & 7) << 3)];
        }
#pragma unroll
        for (int rt = 0; rt < 2; rt++)
#pragma unroll
            for (int ct = 0; ct < 4; ct++)
                acc[rt][ct] = __builtin_amdgcn_mfma_f32_16x16x32_f16(af[rt], bf[ct], acc[rt][ct], 0, 0, 0);
        __syncthreads();
    }
#undef FLOADW
#undef FWRITEW

#pragma unroll
    for (int rt = 0; rt < 2; rt++) {
        int cb = mh * 128 + wid * 32 + rt * 16 + lg * 4;
        float4 g4 = *(const float4*)&gam[cb];
        float4 v4 = *(const float4*)&varr[cb];
        float4 m4 = *(const float4*)&mea[cb];
        float4 t4 = *(const float4*)&bet[cb];
        float4 f4 = *(const float4*)&bfi[cb];
        float iv[4], mn[4], bt[4], bv[4];
        iv[0] = g4.x / sqrtf(v4.x + 1e-5f); iv[1] = g4.y / sqrtf(v4.y + 1e-5f);
        iv[2] = g4.z / sqrtf(v4.z + 1e-5f); iv[3] = g4.w / sqrtf(v4.w + 1e-5f);
        mn[0] = m4.x; mn[1] = m4.y; mn[2] = m4.z; mn[3] = m4.w;
        bt[0] = t4.x; bt[1] = t4.y; bt[2] = t4.z; bt[3] = t4.w;
        bv[0] = f4.x; bv[1] = f4.y; bv[2] = f4.z; bv[3] = f4.w;
#pragma unroll
        for (int ct = 0; ct < 4; ct++) {
            int n = qb * 64 + ct * 16 + l15;
#pragma unroll
            for (int r = 0; r < 4; r++) {
                size_t o = ((size_t)(b * CC + cb + r)) * NN + n;
                out[o] = (acc[rt][ct][r] + bv[r] - mn[r]) * iv[r] + bt[r] + x[o];
            }
        }
    }
}

// ---------------------------------------------------------------------------
extern "C" void kernel_launch(void* const* d_in, const int* in_sizes, int n_in,
                              void* d_out, int out_size, void* d_ws, size_t ws_size,
                              hipStream_t stream)
{
    const int NOUT = BB * CC * NN;   // 8,388,608 elements
    bool sizes_ok = (n_in == 13) && (out_size == NOUT) &&
        in_sizes[0] == NOUT &&
        in_sizes[1] == CI * CC && in_sizes[2] == CI &&
        in_sizes[3] == CI * CC && in_sizes[4] == CI &&
        in_sizes[5] == CI * CC && in_sizes[6] == CI &&
        in_sizes[7] == CC * CI && in_sizes[8] == CC &&
        in_sizes[9] == CC && in_sizes[10] == CC && in_sizes[11] == CC && in_sizes[12] == CC;
    if (!sizes_ok || ws_size < (size_t)WS_NEED) {
        float sig = (!sizes_ok) ? 25000.f : 20000.f;
        hipLaunchKernelGGL(fill_constf, dim3((NOUT + 255) / 256), dim3(256), 0, stream,
                           (float*)d_out, sig, NOUT);
        return;
    }

    const float* x   = (const float*)d_in[0];
    const float* wth = (const float*)d_in[1];
    const float* bth = (const float*)d_in[2];
    const float* wph = (const float*)d_in[3];
    const float* bph = (const float*)d_in[4];
    const float* wg  = (const float*)d_in[5];
    const float* bg  = (const float*)d_in[6];
    const float* wf  = (const float*)d_in[7];
    const float* bfi = (const float*)d_in[8];
    const float* gam = (const float*)d_in[9];
    const float* bet = (const float*)d_in[10];
    const float* mea = (const float*)d_in[11];
    const float* var = (const float*)d_in[12];

    char* ws = (char*)d_ws;
    float* outF = (float*)d_out;                   // 33,554,432 B fp32
    u16*   thH  = (u16*)(outF + 4194304);          // theta fp16: d_out bytes [16MB, 24MB)
    u16*   phHp = (u16*)(ws + PHI_OFF);
    u16*   gHp  = (u16*)(ws + GP_OFF);
    u16*   yH   = (u16*)(ws + Y_OFF);
    u16*   wHi  = (u16*)(ws + WHI_OFF);
    u16*   wLo  = (u16*)(ws + WLO_OFF);
    u16*   wFh  = (u16*)(ws + WFH_OFF);
    u32*   w32  = (u32*)ws;

    hipMemsetAsync(ws + FLAG_OFF, 0, 4, stream);   // flag := 0 (replaces init_flag kernel)
    hipLaunchKernelGGL(probe_x, dim3(1024), dim3(256), 0, stream, (const u32*)x, w32);
    hipLaunchKernelGGL(prep_w, dim3(512), dim3(256), 0, stream,
                       wth, wph, wg, wf, wHi, wLo, wFh);
    hipLaunchKernelGGL(proj_mfma, dim3(128, 3, 4), dim3(256), 0, stream,
                       x, bth, bph, bg, wHi, wLo, thH, phHp, gHp, w32);
    // batch halves: out(b0..b0+1) never clobbers theta rows not yet consumed.
    // out b=0,1 -> bytes [0,16MB); theta lives at [16MB,24MB).
    hipLaunchKernelGGL(attn_mfma, dim3(128, 2), dim3(256), 0, stream, thH, phHp, gHp, yH, 0);
    hipLaunchKernelGGL(final_mfma, dim3(128, 2, 2), dim3(256), 0, stream,
                       yH, wFh, bfi, gam, bet, mea, var, x, w32, outF, 0);
    hipLaunchKernelGGL(attn_mfma, dim3(128, 2), dim3(256), 0, stream, thH, phHp, gHp, yH, 2);
    hipLaunchKernelGGL(final_mfma, dim3(128, 2, 2), dim3(256), 0, stream,
                       yH, wFh, bfi, gam, bet, mea, var, x, w32, outF, 2);
}